// Round 10
// baseline (75.606 us; speedup 1.0000x reference)
//
#include <hip/hip_runtime.h>
#include <hip/hip_bf16.h>
#include <math.h>

typedef short bf16x8 __attribute__((ext_vector_type(8)));
typedef float f32x4 __attribute__((ext_vector_type(4)));
typedef float f32x16 __attribute__((ext_vector_type(16)));
typedef unsigned short u16;
typedef unsigned long long u64;

#define AS1(p) ((const __attribute__((address_space(1))) unsigned int*)(p))
#define AS3(p) ((__attribute__((address_space(3))) unsigned int*)(p))

#define WAITVM2 asm volatile("s_waitcnt vmcnt(2)" ::: "memory")
#define WAITVM1 asm volatile("s_waitcnt vmcnt(1)" ::: "memory")
#define WAITVM0 asm volatile("s_waitcnt vmcnt(0)" ::: "memory")
#define BARRIER asm volatile("s_barrier" ::: "memory")

__device__ __forceinline__ u16 f2bf(float f) {
  union { float f; unsigned u; } v; v.f = f;
  unsigned r = v.u + 0x7fffu + ((v.u >> 16) & 1u);  // RNE
  return (u16)(r >> 16);
}

// ---------- Kernel P: bit-pack adj + row degree (ballot, coalesced) ----------
__global__ __launch_bounds__(256) void k_pack(
    const float* __restrict__ adj, unsigned* __restrict__ bits, float* __restrict__ deg)
{
  const int b   = blockIdx.x & 7;
  const int rg  = blockIdx.x >> 3;        // 0..511
  const int wid = threadIdx.x >> 6;
  const int l   = threadIdx.x & 63;
  const int row = rg * 4 + wid;           // 0..2047
  const float* srcRow = adj + ((size_t)b * 2048 + row) * 2048;

  u64 mine = 0;
  float d = 0.f;
#pragma unroll
  for (int it = 0; it < 32; ++it) {
    const float v = srcRow[it * 64 + l];
    const u64 bal = __ballot(v > 0.f);
    d += (float)__popcll(bal);            // wave-uniform
    if (l == it) mine = bal;
  }
  u64* bitsRow = (u64*)(bits + ((size_t)b * 2048 + row) * 64);
  if (l < 32) bitsRow[l ^ (row & 7)] = mine;
  if (l == 0) deg[(size_t)b * 2048 + row] = d;
}

// ---------- Kernel 0: Wt[f][k] = bf16(W[k][f]) (256x256) ----------
__global__ void k_wt(const float* __restrict__ W, u16* __restrict__ Wt) {
  int idx = blockIdx.x * 256 + threadIdx.x;
#pragma unroll
  for (int q = 0; q < 4; ++q) {
    int i = idx + q * 16384;
    int f = i & 255, k = i >> 8;
    Wt[f * 256 + k] = f2bf(W[k * 256 + f]);
  }
}

// ---------- Kernel A: ht[b][f][j] = bf16( (x @ W)[b,j,f] ) ----------
// bid&7 = batch -> batch b's ht written by XCD-b blocks, stays in its L2.
__global__ __launch_bounds__(512, 4) void k_xw(
    const float* __restrict__ x, const u16* __restrict__ Wt, u16* __restrict__ ht)
{
  __shared__ u16 Ab[2][32 * 64];
  __shared__ u16 Bb[2][256 * 64];

  const int tid = threadIdx.x;
  const int lane = tid & 63;
  const int wid = tid >> 6;
  const int wr = wid >> 2, wc = wid & 3;

  const int b  = blockIdx.x & 7;
  const int jt = blockIdx.x >> 3;
  const int jloc = jt * 32;
  const float* xb = x + ((size_t)b * 2048 + jloc) * 256;
  u16* htb = ht + ((size_t)b << 19);

  const int ar = tid >> 4;
  const int ac = tid & 15;
  const int awb = ar * 128 + ((ac * 8) ^ ((ar & 7) << 4));

  f32x4 acc[4] = {};

  auto stage = [&](int t, int bufi) {
    const float4 v = *(const float4*)(xb + ar * 256 + t * 64 + ac * 4);
    short4 p;
    p.x = (short)f2bf(v.x); p.y = (short)f2bf(v.y);
    p.z = (short)f2bf(v.z); p.w = (short)f2bf(v.w);
    *(short4*)((char*)(&Ab[bufi][0]) + awb) = p;
#pragma unroll
    for (int q = 0; q < 4; ++q) {
      const int fbase = wid * 32 + q * 8;
      const int f = fbase + (lane >> 3);
      const char* src = (const char*)Wt + f * 512 + t * 128
                        + (((lane & 7) * 16) ^ ((f & 7) << 4));
      __builtin_amdgcn_global_load_lds(AS1(src),
          AS3((char*)(&Bb[bufi][0]) + fbase * 128), 16, 0, 0);
    }
  };

  auto compute = [&](int bufi) {
#pragma unroll
    for (int kk = 0; kk < 2; ++kk) {
      const int am = wr * 16 + (lane & 15);
      const bf16x8 a = *(const bf16x8*)((const char*)(&Ab[bufi][0])
          + am * 128 + ((kk * 64 + (lane >> 4) * 16) ^ ((am & 7) << 4)));
#pragma unroll
      for (int nf = 0; nf < 4; ++nf) {
        const int bn = wc * 64 + nf * 16 + (lane & 15);
        const bf16x8 bv = *(const bf16x8*)((const char*)(&Bb[bufi][0])
            + bn * 128 + ((kk * 64 + (lane >> 4) * 16) ^ ((bn & 7) << 4)));
        acc[nf] = __builtin_amdgcn_mfma_f32_16x16x32_bf16(a, bv, acc[nf], 0, 0, 0);
      }
    }
  };

  stage(0, 0);
  __syncthreads();
#pragma unroll 2
  for (int t = 0; t < 4; ++t) {
    const int cur = t & 1;
    if (t + 1 < 4) stage(t + 1, cur ^ 1);
    compute(cur);
    __syncthreads();
  }

  const int j0 = jloc + wr * 16 + ((lane >> 4) << 2);
#pragma unroll
  for (int nf = 0; nf < 4; ++nf) {
    const int f = wc * 64 + nf * 16 + (lane & 15);
    short4 p;
    p.x = (short)f2bf(acc[nf][0]);
    p.y = (short)f2bf(acc[nf][1]);
    p.z = (short)f2bf(acc[nf][2]);
    p.w = (short)f2bf(acc[nf][3]);
    *(short4*)(&htb[(size_t)f * 2048 + j0]) = p;
  }
}

// ---------- Kernel B: out = elu( (1/deg) * adj @ h ) ----------
// BM=256, BN=64: grid 256 = 8b x 8rt x 4nt (bid&7=b). B-restream halved to
// 64 MB total; per-block B = 256 KB vs 2048 MFMA (4x arithmetic intensity
// of r8). bits for all 256 rows (64 KB) in LDS prologue; in-loop staging is
// 1 gload_lds/thread (B only), ring-4, counted WAITVM2, one barrier/iter.
// Same bit-expand + 32x32x16 mapping that passed r8/r9.
__global__ __launch_bounds__(512, 1) void k_agg(
    const unsigned* __restrict__ bits, const float* __restrict__ deg,
    const u16* __restrict__ ht, float* __restrict__ out)
{
  __shared__ unsigned bitsLds[256 * 64];   // 64 KB, pre-swizzled 8B units
  __shared__ u16 Bbuf[4][64 * 64];         // 8 KB x4: ht [64f][64k], slot^(f&7)

  const int tid  = threadIdx.x;
  const int lane = tid & 63;
  const int wid  = tid >> 6;               // 0..7 = sm strip (32 rows each)

  const int b  = blockIdx.x & 7;
  const int nt = (blockIdx.x >> 3) & 3;    // 0..3: 64-f strip
  const int rt = blockIdx.x >> 5;          // 0..7: 256-row tile
  const int row0 = rt * 256;

  const char* bsrc = (const char*)(bits + ((size_t)b * 2048 + row0) * 64);
  const char* htB  = (const char*)ht + ((size_t)b << 20);
  const float* degB = deg + (size_t)b * 2048 + row0;
  float* outb = out + ((size_t)b * 2048 + row0) * 256 + nt * 64;

  // prologue: 64 KB bits -> LDS, linear (source pre-swizzled by k_pack): 8 loads
#pragma unroll
  for (int q = 0; q < 8; ++q) {
    __builtin_amdgcn_global_load_lds(AS1(bsrc + q * 8192 + wid * 1024 + (lane & 63) * 16),
        AS3((char*)bitsLds + q * 8192 + wid * 1024), 16, 0, 0);
  }

  // B stage: 1 gload_lds/thread per tile (8 KB/block)
  auto stage = [&](int t, int r) {
    const int floc = wid * 8 + (lane >> 3);          // 0..63
    const int s = lane & 7;
    const char* src = htB + (size_t)(nt * 64 + floc) * 4096 + (size_t)t * 128
                      + ((s ^ (floc & 7)) * 16);
    __builtin_amdgcn_global_load_lds(AS1(src),
        AS3((char*)(&Bbuf[r][0]) + wid * 1024), 16, 0, 0);
  };

  f32x16 acc[2] = {};
  const int lo = lane & 31;
  const int hi = lane >> 5;
  const int arow = wid * 32 + lo;          // 0..255

  stage(0, 0);
  stage(1, 1);
  stage(2, 2);

  for (int t = 0; t < 32; ++t) {
    if (t <= 29) { WAITVM2; } else if (t == 30) { WAITVM1; } else { WAITVM0; }
    BARRIER;
    const int r = t & 3;
    if (t < 29) stage(t + 3, (t + 3) & 3);           // slot freed at t-1
    const u64 rowbits = *(const u64*)((const char*)bitsLds
        + arow * 256 + ((t ^ (arow & 7)) * 8));
    const char* Bb = (const char*)(&Bbuf[r][0]);
#pragma unroll
    for (int ksl = 0; ksl < 4; ++ksl) {
      const unsigned byte = (unsigned)(rowbits >> ((ksl * 2 + hi) * 8)) & 0xFFu;
      union { bf16x8 v; unsigned u[4]; } af;
#pragma unroll
      for (int w = 0; w < 4; ++w) {
        const unsigned l16 = ((byte >> (2 * w)) & 1u) * 0x3F80u;
        const unsigned h16 = ((byte >> (2 * w + 1)) & 1u) * 0x3F80u;
        af.u[w] = l16 | (h16 << 16);
      }
#pragma unroll
      for (int nf = 0; nf < 2; ++nf) {
        const int floc = nf * 32 + lo;
        const bf16x8 bv = *(const bf16x8*)(Bb + floc * 128
            + (((ksl * 2 + hi) ^ (floc & 7)) * 16));
        acc[nf] = __builtin_amdgcn_mfma_f32_32x32x16_bf16(af.v, bv, acc[nf], 0, 0, 0);
      }
    }
  }

  // epilogue: C/D 32x32: col = lane&31, row = (reg&3)+8*(reg>>2)+4*hi
#pragma unroll
  for (int reg = 0; reg < 16; ++reg) {
    const int rl = (reg & 3) + 8 * (reg >> 2) + 4 * hi;
    const float d = degB[wid * 32 + rl];
    const float sc = d > 0.f ? 1.f / d : (1.f / 2048.f);
    float* orow = outb + (size_t)(wid * 32 + rl) * 256 + lo;
#pragma unroll
    for (int nf = 0; nf < 2; ++nf) {
      const float v = acc[nf][reg] * sc;
      orow[nf * 32] = v > 0.f ? v : expm1f(v);
    }
  }
}

extern "C" void kernel_launch(void* const* d_in, const int* in_sizes, int n_in,
                              void* d_out, int out_size, void* d_ws, size_t ws_size,
                              hipStream_t stream) {
  const float* x   = (const float*)d_in[0];
  const float* adj = (const float*)d_in[1];
  const float* W   = (const float*)d_in[2];
  // d_in[3] ('a') is mathematically dead: softmax rows are constant over the
  // active (adj>0) entries, so attention = 1/deg regardless of e.
  float* out = (float*)d_out;

  u16*      Wt   = (u16*)d_ws;                              // 128 KB
  u16*      ht   = (u16*)((char*)d_ws + 131072);            // 8 MB
  unsigned* bits = (unsigned*)((char*)d_ws + 8519680);      // 4 MB
  float*    degp = (float*)((char*)d_ws + 12713984);        // 64 KB

  // k_pack FIRST: its 134 MB adj stream must not evict ht from L2.
  k_pack<<<4096, 256, 0, stream>>>(adj, bits, degp);
  k_wt<<<64, 256, 0, stream>>>(W, Wt);
  k_xw<<<512, 512, 0, stream>>>(x, Wt, ht);
  k_agg<<<256, 512, 0, stream>>>(bits, degp, ht, out);
}

// Round 11
// 65.222 us; speedup vs baseline: 1.1592x; 1.1592x over previous
//
#include <hip/hip_runtime.h>
#include <hip/hip_bf16.h>
#include <math.h>

typedef short bf16x8 __attribute__((ext_vector_type(8)));
typedef float f32x4 __attribute__((ext_vector_type(4)));
typedef unsigned short u16;

#define AS1(p) ((const __attribute__((address_space(1))) unsigned int*)(p))
#define AS3(p) ((__attribute__((address_space(3))) unsigned int*)(p))

#define WAITVM3 asm volatile("s_waitcnt vmcnt(3)" ::: "memory")
#define WAITVM0 asm volatile("s_waitcnt vmcnt(0)" ::: "memory")
#define LGKM0   asm volatile("s_waitcnt lgkmcnt(0)" ::: "memory")
#define BARRIER asm volatile("s_barrier" ::: "memory")

__device__ __forceinline__ u16 f2bf(float f) {
  union { float f; unsigned u; } v; v.f = f;
  unsigned r = v.u + 0x7fffu + ((v.u >> 16) & 1u);  // RNE
  return (u16)(r >> 16);
}

// ---------- Kernel 0: Wt[f][k] = bf16(W[k][f]) (256x256) ----------
__global__ void k_wt(const float* __restrict__ W, u16* __restrict__ Wt) {
  int idx = blockIdx.x * 256 + threadIdx.x;
#pragma unroll
  for (int q = 0; q < 4; ++q) {
    int i = idx + q * 16384;
    int f = i & 255, k = i >> 8;
    Wt[f * 256 + k] = f2bf(W[k * 256 + f]);
  }
}

// ---------- Kernel A: ht[b][f][j] = bf16( (x @ W)[b,j,f] ) ----------
// bid&7 = batch -> batch b's ht written by XCD-b blocks, stays in its L2.
__global__ __launch_bounds__(512, 4) void k_xw(
    const float* __restrict__ x, const u16* __restrict__ Wt, u16* __restrict__ ht)
{
  __shared__ u16 Ab[2][32 * 64];
  __shared__ u16 Bb[2][256 * 64];

  const int tid = threadIdx.x;
  const int lane = tid & 63;
  const int wid = tid >> 6;
  const int wr = wid >> 2, wc = wid & 3;

  const int b  = blockIdx.x & 7;
  const int jt = blockIdx.x >> 3;
  const int jloc = jt * 32;
  const float* xb = x + ((size_t)b * 2048 + jloc) * 256;
  u16* htb = ht + ((size_t)b << 19);

  const int ar = tid >> 4;
  const int ac = tid & 15;
  const int awb = ar * 128 + ((ac * 8) ^ ((ar & 7) << 4));

  f32x4 acc[4] = {};

  auto stage = [&](int t, int bufi) {
    const float4 v = *(const float4*)(xb + ar * 256 + t * 64 + ac * 4);
    short4 p;
    p.x = (short)f2bf(v.x); p.y = (short)f2bf(v.y);
    p.z = (short)f2bf(v.z); p.w = (short)f2bf(v.w);
    *(short4*)((char*)(&Ab[bufi][0]) + awb) = p;
#pragma unroll
    for (int q = 0; q < 4; ++q) {
      const int fbase = wid * 32 + q * 8;
      const int f = fbase + (lane >> 3);
      const char* src = (const char*)Wt + f * 512 + t * 128
                        + (((lane & 7) * 16) ^ ((f & 7) << 4));
      __builtin_amdgcn_global_load_lds(AS1(src),
          AS3((char*)(&Bb[bufi][0]) + fbase * 128), 16, 0, 0);
    }
  };

  auto compute = [&](int bufi) {
#pragma unroll
    for (int kk = 0; kk < 2; ++kk) {
      const int am = wr * 16 + (lane & 15);
      const bf16x8 a = *(const bf16x8*)((const char*)(&Ab[bufi][0])
          + am * 128 + ((kk * 64 + (lane >> 4) * 16) ^ ((am & 7) << 4)));
#pragma unroll
      for (int nf = 0; nf < 4; ++nf) {
        const int bn = wc * 64 + nf * 16 + (lane & 15);
        const bf16x8 bv = *(const bf16x8*)((const char*)(&Bb[bufi][0])
            + bn * 128 + ((kk * 64 + (lane >> 4) * 16) ^ ((bn & 7) << 4)));
        acc[nf] = __builtin_amdgcn_mfma_f32_16x16x32_bf16(a, bv, acc[nf], 0, 0, 0);
      }
    }
  };

  stage(0, 0);
  __syncthreads();
#pragma unroll 2
  for (int t = 0; t < 4; ++t) {
    const int cur = t & 1;
    if (t + 1 < 4) stage(t + 1, cur ^ 1);
    compute(cur);
    __syncthreads();
  }

  const int j0 = jloc + wr * 16 + ((lane >> 4) << 2);
#pragma unroll
  for (int nf = 0; nf < 4; ++nf) {
    const int f = wc * 64 + nf * 16 + (lane & 15);
    short4 p;
    p.x = (short)f2bf(acc[nf][0]);
    p.y = (short)f2bf(acc[nf][1]);
    p.z = (short)f2bf(acc[nf][2]);
    p.w = (short)f2bf(acc[nf][3]);
    *(short4*)(&htb[(size_t)f * 2048 + j0]) = p;
  }
}

// ---------- Kernel B: out = elu( (1/deg) * adj @ h ) ----------
// r3 pipeline, 2x the waves: 512 blocks x 1024 thr (16 waves), BM=32, BN=256,
// BK=64, dbuf + counted vmcnt(3). LDS 72 KB -> 2 blocks/CU -> 32 waves/CU
// (HW max). Wave tile 16m x 32f (acc[2], VGPR-lean). adj read once; deg from
// A-staging partials + 32-lane shfl reduce.
__global__ __launch_bounds__(1024, 8) void k_agg(
    const float* __restrict__ adj, const u16* __restrict__ ht, float* __restrict__ out)
{
  __shared__ u16 Ab[2][32 * 64];    // 4 KB x2: adj tile [32r][64k] bf16, slot^(r&7)
  __shared__ u16 Bb[2][256 * 64];   // 32 KB x2: ht [256f][64k] bf16, slot^(f&7)

  const int tid = threadIdx.x;      // 0..1023
  const int lane = tid & 63;
  const int wid = tid >> 6;         // 0..15
  const int wr = wid >> 3;          // 0..1: 16-row strip
  const int wc = wid & 7;           // 0..7: 32-f strip

  const int b  = blockIdx.x & 7;    // batch -> XCD-local ht in L2
  const int rt = blockIdx.x >> 3;   // 0..63
  const int row0 = rt * 32;

  const float* adjb = adj + ((size_t)b * 2048 + row0) * 2048;
  const u16* htb = ht + ((size_t)b << 19);
  float* outb = out + ((size_t)b * 2048 + row0) * 256;

  const int ar = tid >> 5;          // 0..31: A row
  const int ac = tid & 31;          // 0..31: float2 slot
  const int awb = ar * 128 + ((((ac >> 2) ^ (ar & 7)) << 4) | ((ac & 3) * 4));

  float deg = 0.f;
  f32x4 acc[2] = {};
  float2 rA0, rA1;

  // per stage: 1 A float2 + 2 B gload_lds = 3 VMEM/thread
  auto stage = [&](int t, float2& rA) {
    rA = *(const float2*)(adjb + (size_t)ar * 2048 + t * 64 + ac * 2);
#pragma unroll
    for (int q = 0; q < 2; ++q) {
      const int f = q * 128 + wid * 8 + (lane >> 3);
      const int s = lane & 7;
      const char* src = (const char*)htb + (size_t)f * 4096 + (size_t)t * 128
                        + ((s ^ (f & 7)) * 16);
      __builtin_amdgcn_global_load_lds(AS1(src),
          AS3((char*)(&Bb[t & 1][0]) + q * 16384 + wid * 1024), 16, 0, 0);
    }
  };

  auto writeA = [&](int bufi, float2& rA) {
    deg += rA.x + rA.y;                       // adj is 0/1 -> exact
    union { float f; unsigned u; } x0, x1; x0.f = rA.x; x1.f = rA.y;
    const unsigned pk = (x0.u >> 16) | (x1.u & 0xFFFF0000u);  // trunc exact
    *(unsigned*)((char*)(&Ab[bufi][0]) + awb) = pk;
  };

  auto compute = [&](int bufi) {
    const int g = lane >> 4;
    const int c = lane & 15;
    const int am = wr * 16 + c;
#pragma unroll
    for (int kk = 0; kk < 2; ++kk) {
      const bf16x8 a = *(const bf16x8*)((const char*)(&Ab[bufi][0])
          + am * 128 + ((kk * 64 + g * 16) ^ ((am & 7) << 4)));
#pragma unroll
      for (int nf = 0; nf < 2; ++nf) {
        const int bn = wc * 32 + nf * 16 + c;
        const bf16x8 bv = *(const bf16x8*)((const char*)(&Bb[bufi][0])
            + bn * 128 + ((kk * 64 + g * 16) ^ ((bn & 7) << 4)));
        acc[nf] = __builtin_amdgcn_mfma_f32_16x16x32_bf16(a, bv, acc[nf], 0, 0, 0);
      }
    }
  };

  stage(0, rA0);                    // 3 VMEM in flight
  stage(1, rA1);                    // 6 in flight
  for (int t = 0; t < 31; ++t) {
    const int cur = t & 1;
    WAITVM3;                        // oldest 3 = tile t landed; t+1 in flight
    writeA(cur, cur ? rA1 : rA0);
    LGKM0;
    BARRIER;
    compute(cur);
    LGKM0;
    BARRIER;                        // buffer cur free for reuse
    if (t < 30) stage(t + 2, cur ? rA1 : rA0);
  }
  WAITVM0;
  writeA(1, rA1);
  LGKM0;
  BARRIER;
  compute(1);

  // deg: reduce across the 32 threads (ac) of row ar (stays within 32-lane half)
#pragma unroll
  for (int s = 1; s < 32; s <<= 1) deg += __shfl_xor(deg, s);
  float* degLds = (float*)&Ab[0][0];   // Ab[0] dead (last read t=30)
  if (ac == 0) degLds[ar] = deg;
  __syncthreads();

  // epilogue: C/D 16x16: col = lane&15, row = (lane>>4)*4 + r
  const int g = lane >> 4;
  const int c = lane & 15;
  float sc[4];
#pragma unroll
  for (int r = 0; r < 4; ++r) {
    const float d = degLds[wr * 16 + g * 4 + r];
    sc[r] = d > 0.f ? 1.f / d : (1.f / 2048.f);
  }
#pragma unroll
  for (int nf = 0; nf < 2; ++nf) {
    const int f = wc * 32 + nf * 16 + c;
#pragma unroll
    for (int r = 0; r < 4; ++r) {
      const float v = acc[nf][r] * sc[r];
      outb[(size_t)(wr * 16 + g * 4 + r) * 256 + f] = v > 0.f ? v : expm1f(v);
    }
  }
}

extern "C" void kernel_launch(void* const* d_in, const int* in_sizes, int n_in,
                              void* d_out, int out_size, void* d_ws, size_t ws_size,
                              hipStream_t stream) {
  const float* x   = (const float*)d_in[0];
  const float* adj = (const float*)d_in[1];
  const float* W   = (const float*)d_in[2];
  // d_in[3] ('a') is mathematically dead: softmax rows are constant over the
  // active (adj>0) entries, so attention = 1/deg regardless of e.
  float* out = (float*)d_out;

  u16* Wt = (u16*)d_ws;                          // 128 KB
  u16* ht = (u16*)((char*)d_ws + 131072);        // 8 MB

  k_wt<<<64, 256, 0, stream>>>(W, Wt);
  k_xw<<<512, 512, 0, stream>>>(x, Wt, ht);
  k_agg<<<512, 1024, 0, stream>>>(adj, ht, out);
}